// Round 2
// baseline (345.962 us; speedup 1.0000x reference)
//
#include <hip/hip_runtime.h>
#include <hip/hip_bf16.h>

// KL-style loss: mean_n [ -sum_y target[n,y] * log_softmax(pred)[n,y] ]
// N = 4194304 rows, C = 10, fp32 in, scalar fp32 out.
//
// Identity used: loss_total = sum_{n,y} t[n,y] * (lse_n - x[n,y])
// -> only lse needs row structure; t and x are consumed elementwise in
//    fully-coalesced register layout. Only pred is staged through LDS.

#define N_ROWS 4194304
#define C_DIM 10
#define BLOCK 256
#define ROWS_PER_BLOCK 512                        // 2 rows per thread
#define WORDS_PER_BLOCK (ROWS_PER_BLOCK * C_DIM)  // 5120 floats per array
#define F4_PER_THREAD 5                           // 5120/4/256
#define LDS_PAD 513                               // column length pad: bank=(y+r)%32

__global__ __launch_bounds__(BLOCK) void kl_loss_kernel(
    const float* __restrict__ pred,
    const float* __restrict__ tgt,
    float* __restrict__ out)
{
    __shared__ float sp[C_DIM][LDS_PAD];     // pred tile, column-major sp[y][r]
    __shared__ float slse[ROWS_PER_BLOCK];   // per-row logsumexp
    __shared__ float sred[BLOCK / 64];       // final block reduction

    const int tid = threadIdx.x;
    const size_t blk_f4 = (size_t)blockIdx.x * (WORDS_PER_BLOCK / 4);

    const float4* p4 = reinterpret_cast<const float4*>(pred);
    const float4* t4 = reinterpret_cast<const float4*>(tgt);

    // ---- Phase 1: coalesced loads (each instruction: 64 contiguous float4) ----
    float4 pv[F4_PER_THREAD], tv[F4_PER_THREAD];
#pragma unroll
    for (int i = 0; i < F4_PER_THREAD; ++i)
        pv[i] = p4[blk_f4 + i * BLOCK + tid];
#pragma unroll
    for (int i = 0; i < F4_PER_THREAD; ++i)
        tv[i] = t4[blk_f4 + i * BLOCK + tid];   // in flight through phase 2

    // scatter pred into column-major LDS
#pragma unroll
    for (int i = 0; i < F4_PER_THREAD; ++i) {
        int w = (i * BLOCK + tid) * 4;          // word offset in block tile
        int r = w / C_DIM;
        int y = w - r * C_DIM;
        float e[4] = {pv[i].x, pv[i].y, pv[i].z, pv[i].w};
#pragma unroll
        for (int c = 0; c < 4; ++c) {
            sp[y][r] = e[c];
            ++y;
            if (y == C_DIM) { y = 0; ++r; }
        }
    }
    __syncthreads();

    // ---- Phase 2: per-row logsumexp (conflict-free column reads) ----
#pragma unroll
    for (int half = 0; half < 2; ++half) {
        int r = tid + half * BLOCK;
        float x[C_DIM];
#pragma unroll
        for (int y = 0; y < C_DIM; ++y) x[y] = sp[y][r];
        float m = x[0];
#pragma unroll
        for (int y = 1; y < C_DIM; ++y) m = fmaxf(m, x[y]);
        float s = 0.0f;
#pragma unroll
        for (int y = 0; y < C_DIM; ++y) s += __expf(x[y] - m);
        slse[r] = m + __logf(s);
    }
    __syncthreads();

    // ---- Phase 3: elementwise t*(lse - x) from registers ----
    float acc = 0.0f;
#pragma unroll
    for (int i = 0; i < F4_PER_THREAD; ++i) {
        int w = (i * BLOCK + tid) * 4;
        int r = w / C_DIM;
        int y = w - r * C_DIM;
        float pe[4] = {pv[i].x, pv[i].y, pv[i].z, pv[i].w};
        float te[4] = {tv[i].x, tv[i].y, tv[i].z, tv[i].w};
#pragma unroll
        for (int c = 0; c < 4; ++c) {
            acc = fmaf(te[c], slse[r] - pe[c], acc);
            ++y;
            if (y == C_DIM) { y = 0; ++r; }
        }
    }

    // ---- Reduction: wave shuffle -> LDS -> one atomic per block ----
#pragma unroll
    for (int off = 32; off > 0; off >>= 1)
        acc += __shfl_down(acc, off, 64);

    const int lane = tid & 63;
    const int wid  = tid >> 6;
    if (lane == 0) sred[wid] = acc;
    __syncthreads();

    if (tid == 0) {
        float b = sred[0] + sred[1] + sred[2] + sred[3];
        atomicAdd(out, b * (1.0f / (float)N_ROWS));
    }
}

extern "C" void kernel_launch(void* const* d_in, const int* in_sizes, int n_in,
                              void* d_out, int out_size, void* d_ws, size_t ws_size,
                              hipStream_t stream)
{
    const float* pred = (const float*)d_in[0];
    const float* tgt  = (const float*)d_in[1];
    float* out = (float*)d_out;

    // d_out is poisoned (0xAA) before every call; zero it for the atomic accumulate.
    hipMemsetAsync(out, 0, sizeof(float), stream);

    const int blocks = N_ROWS / ROWS_PER_BLOCK;   // 8192
    kl_loss_kernel<<<blocks, BLOCK, 0, stream>>>(pred, tgt, out);
}